// Round 3
// baseline (7540.905 us; speedup 1.0000x reference)
//
#include <hip/hip_runtime.h>
#include <math.h>

// ---------------------------------------------------------------------------
// Transformer block (B=8, S=2048, E=1024), fp32 baseline, ws-lean version.
//
// Workspace layout (adaptive): t0,t1,t2 = 64 MB each; sc = 8*qc*2048*4 bytes
// where qc in {512,256,128,64} is the largest that fits ws_size. <= 224 MB.
//
// Liveness plan (in-place tricks marked *):
//  1. Q  = in@Wq   -> t0
//  2. K  = in@Wk   -> t1
//  3. V  = in@Wv   -> t2
//  4. per q-chunk c: sc = Q[c] K^T /32 (causal tile-skip); softmax(causal);
//     O[c] = P V  -> t0[c]  (* overwrites Q chunk; safe: Q[c] already consumed)
//  5. h  = LN(t0 + in) -> t0 (* in-place row-wise)
//  6. Q2 = t0@Wcq  -> t1
//  7. K2 = ctx@Wck -> t2
//  8. V2 = ctx@Wcv -> d_out
//  9. per q-chunk: sc = Q2[c] K2^T /32; softmax; O2[c] = P V2 -> t1[c] (*)
// 10. h2 = LN(t1 + t0) -> t1 (* in-place)
// 11. f  = relu(t1@W1 + b1) -> t2
// 12. out = relu(LN(t2 + t1)) -> d_out
// ---------------------------------------------------------------------------

#define TM 128
#define TN 128
#define TK 16

__device__ __forceinline__ float wave_reduce_sum(float v) {
#pragma unroll
  for (int m = 32; m >= 1; m >>= 1) v += __shfl_xor(v, m, 64);
  return v;
}
__device__ __forceinline__ float wave_reduce_max(float v) {
#pragma unroll
  for (int m = 32; m >= 1; m >>= 1) v = fmaxf(v, __shfl_xor(v, m, 64));
  return v;
}
// blockDim.x must be 256 (4 waves)
__device__ __forceinline__ float block_reduce_sum(float v, float* red) {
  v = wave_reduce_sum(v);
  if ((threadIdx.x & 63) == 0) red[threadIdx.x >> 6] = v;
  __syncthreads();
  const float r = red[0] + red[1] + red[2] + red[3];
  __syncthreads();
  return r;
}
__device__ __forceinline__ float block_reduce_max(float v, float* red) {
  v = wave_reduce_max(v);
  if ((threadIdx.x & 63) == 0) red[threadIdx.x >> 6] = v;
  __syncthreads();
  const float r = fmaxf(fmaxf(red[0], red[1]), fmaxf(red[2], red[3]));
  __syncthreads();
  return r;
}

// C[b][m][n] = act(alpha * sum_k A[b][m][k] * B[b][k][n] + bias[n])
// B is K x N row-major (weights layout).
// KCAP: Keff = min(K, mofs + m0 + TM)  (causal PV upper bound).
template <bool HASBIAS, bool RELU, bool KCAP>
__global__ __launch_bounds__(256) void gemm_nn(
    const float* __restrict__ A, const float* __restrict__ B,
    float* __restrict__ C, const float* __restrict__ bias,
    int N, int K,
    long long sA, long long sB, long long sC, float alpha, int mofs) {
  const int b = blockIdx.z;
  A += (long long)b * sA;
  B += (long long)b * sB;
  C += (long long)b * sC;
  const int m0 = blockIdx.y * TM;
  const int n0 = blockIdx.x * TN;
  const int tid = threadIdx.x;
  const int ty = tid >> 4, tx = tid & 15;
  int Keff = K;
  if (KCAP) Keff = min(K, mofs + m0 + TM);

  __shared__ float As[TK][TM + 4];
  __shared__ float Bs[TK][TN + 4];

  float acc[8][8];
#pragma unroll
  for (int i = 0; i < 8; ++i)
#pragma unroll
    for (int j = 0; j < 8; ++j) acc[i][j] = 0.f;

  for (int k0 = 0; k0 < Keff; k0 += TK) {
    // A tile: 128 rows x 16 cols (float4 along K, store transposed)
    for (int s = tid; s < 512; s += 256) {
      const int row = s >> 2;
      const int kc = (s & 3) << 2;
      const float4 v =
          *(const float4*)(A + (long long)(m0 + row) * K + (k0 + kc));
      As[kc + 0][row] = v.x;
      As[kc + 1][row] = v.y;
      As[kc + 2][row] = v.z;
      As[kc + 3][row] = v.w;
    }
    // B tile: 16 rows x 128 cols (natural layout, float4 stores)
    for (int s = tid; s < 512; s += 256) {
      const int row = s >> 5;
      const int col = (s & 31) << 2;
      *(float4*)&Bs[row][col] =
          *(const float4*)(B + (long long)(k0 + row) * N + (n0 + col));
    }
    __syncthreads();
#pragma unroll
    for (int kk = 0; kk < TK; ++kk) {
      float a[8], bb[8];
      *(float4*)&a[0] = *(const float4*)&As[kk][ty * 8];
      *(float4*)&a[4] = *(const float4*)&As[kk][ty * 8 + 4];
      *(float4*)&bb[0] = *(const float4*)&Bs[kk][tx * 8];
      *(float4*)&bb[4] = *(const float4*)&Bs[kk][tx * 8 + 4];
#pragma unroll
      for (int i = 0; i < 8; ++i)
#pragma unroll
        for (int j = 0; j < 8; ++j) acc[i][j] = fmaf(a[i], bb[j], acc[i][j]);
    }
    __syncthreads();
  }
#pragma unroll
  for (int i = 0; i < 8; ++i) {
    const long long m = (long long)m0 + ty * 8 + i;
    float* crow = C + m * (long long)N + n0 + tx * 8;
#pragma unroll
    for (int j4 = 0; j4 < 8; j4 += 4) {
      float4 v;
      v.x = acc[i][j4 + 0] * alpha;
      v.y = acc[i][j4 + 1] * alpha;
      v.z = acc[i][j4 + 2] * alpha;
      v.w = acc[i][j4 + 3] * alpha;
      if (HASBIAS) {
        const float4 bv = *(const float4*)(bias + n0 + tx * 8 + j4);
        v.x += bv.x;
        v.y += bv.y;
        v.z += bv.z;
        v.w += bv.w;
      }
      if (RELU) {
        v.x = fmaxf(v.x, 0.f);
        v.y = fmaxf(v.y, 0.f);
        v.z = fmaxf(v.z, 0.f);
        v.w = fmaxf(v.w, 0.f);
      }
      *(float4*)(crow + j4) = v;
    }
  }
}

// C[b][m][n] = alpha * sum_k A[b][m][k] * Bm[b][n][k]   (both row-major, NT)
// CAUSAL: skip tiles entirely above the diagonal (global row = mofs + local m).
template <bool CAUSAL>
__global__ __launch_bounds__(256) void gemm_nt(
    const float* __restrict__ A, const float* __restrict__ Bm,
    float* __restrict__ C,
    int N, int K,
    long long sA, long long sB, long long sC, float alpha, int mofs) {
  const int m0 = blockIdx.y * TM;
  const int n0 = blockIdx.x * TN;
  if (CAUSAL && n0 >= mofs + m0 + TM) return;  // tile fully masked
  const int b = blockIdx.z;
  const float* Ab = A + (long long)b * sA;
  const float* Bb = Bm + (long long)b * sB;
  float* Cb = C + (long long)b * sC;
  const int tid = threadIdx.x;
  const int ty = tid >> 4, tx = tid & 15;

  __shared__ float As[TK][TM + 4];
  __shared__ float Bs[TK][TN + 4];

  float acc[8][8];
#pragma unroll
  for (int i = 0; i < 8; ++i)
#pragma unroll
    for (int j = 0; j < 8; ++j) acc[i][j] = 0.f;

  for (int k0 = 0; k0 < K; k0 += TK) {
    for (int s = tid; s < 512; s += 256) {
      const int row = s >> 2;
      const int kc = (s & 3) << 2;
      const float4 v =
          *(const float4*)(Ab + (long long)(m0 + row) * K + (k0 + kc));
      As[kc + 0][row] = v.x;
      As[kc + 1][row] = v.y;
      As[kc + 2][row] = v.z;
      As[kc + 3][row] = v.w;
    }
    for (int s = tid; s < 512; s += 256) {
      const int row = s >> 2;
      const int kc = (s & 3) << 2;
      const float4 v =
          *(const float4*)(Bb + (long long)(n0 + row) * K + (k0 + kc));
      Bs[kc + 0][row] = v.x;
      Bs[kc + 1][row] = v.y;
      Bs[kc + 2][row] = v.z;
      Bs[kc + 3][row] = v.w;
    }
    __syncthreads();
#pragma unroll
    for (int kk = 0; kk < TK; ++kk) {
      float a[8], bb[8];
      *(float4*)&a[0] = *(const float4*)&As[kk][ty * 8];
      *(float4*)&a[4] = *(const float4*)&As[kk][ty * 8 + 4];
      *(float4*)&bb[0] = *(const float4*)&Bs[kk][tx * 8];
      *(float4*)&bb[4] = *(const float4*)&Bs[kk][tx * 8 + 4];
#pragma unroll
      for (int i = 0; i < 8; ++i)
#pragma unroll
        for (int j = 0; j < 8; ++j) acc[i][j] = fmaf(a[i], bb[j], acc[i][j]);
    }
    __syncthreads();
  }
#pragma unroll
  for (int i = 0; i < 8; ++i) {
    const long long m = (long long)m0 + ty * 8 + i;
    float* crow = Cb + m * (long long)N + n0 + tx * 8;
#pragma unroll
    for (int j4 = 0; j4 < 8; j4 += 4) {
      float4 v;
      v.x = acc[i][j4 + 0] * alpha;
      v.y = acc[i][j4 + 1] * alpha;
      v.z = acc[i][j4 + 2] * alpha;
      v.w = acc[i][j4 + 3] * alpha;
      *(float4*)(crow + j4) = v;
    }
  }
}

// Row softmax over ncols=2048 (256 thr x 8 elems).
// Scores layout [B][qc][ncols]; global q-row = qofs + (blockIdx.x % qc).
__global__ __launch_bounds__(256) void softmax_rows(
    float* __restrict__ S, int ncols, int qc, int causal, int qofs) {
  __shared__ float red[4];
  const long long r = blockIdx.x;
  const int q = qofs + (int)(r % qc);
  float* row = S + r * (long long)ncols;
  const int tid = threadIdx.x;
  float v[8];
  *(float4*)&v[0] = *(const float4*)(row + tid * 8);
  *(float4*)&v[4] = *(const float4*)(row + tid * 8 + 4);
  if (causal) {
#pragma unroll
    for (int j = 0; j < 8; ++j)
      if (tid * 8 + j > q) v[j] = -INFINITY;
  }
  float m = -INFINITY;
#pragma unroll
  for (int j = 0; j < 8; ++j) m = fmaxf(m, v[j]);
  m = block_reduce_max(m, red);
  float s = 0.f;
#pragma unroll
  for (int j = 0; j < 8; ++j) {
    v[j] = __expf(v[j] - m);  // exp(-inf)=0 handles masked entries
    s += v[j];
  }
  s = block_reduce_sum(s, red);
  const float inv = 1.0f / s;
#pragma unroll
  for (int j = 0; j < 8; ++j) v[j] *= inv;
  *(float4*)(row + tid * 8) = *(float4*)&v[0];
  *(float4*)(row + tid * 8 + 4) = *(float4*)&v[4];
}

// out[r] = (relu?) LN(X[r] + Y[r]); eps=1e-3; E=1024; 256 thr. In-place-safe
// when out==X or out==Y (row-private, reads complete before writes).
template <bool RELU_OUT>
__global__ __launch_bounds__(256) void add_ln(
    const float* __restrict__ X, const float* __restrict__ Y,
    const float* __restrict__ gamma, const float* __restrict__ beta,
    float* __restrict__ out, int E) {
  __shared__ float red[4];
  const long long r = blockIdx.x;
  const int tid = threadIdx.x;
  const float invE = 1.0f / (float)E;
  const float4 a = *(const float4*)(X + r * (long long)E + tid * 4);
  const float4 b = *(const float4*)(Y + r * (long long)E + tid * 4);
  float v[4] = {a.x + b.x, a.y + b.y, a.z + b.z, a.w + b.w};
  float s = v[0] + v[1] + v[2] + v[3];
  s = block_reduce_sum(s, red);
  const float mu = s * invE;
  float d[4], sq = 0.f;
#pragma unroll
  for (int j = 0; j < 4; ++j) {
    d[j] = v[j] - mu;
    sq += d[j] * d[j];
  }
  sq = block_reduce_sum(sq, red);
  const float rs = rsqrtf(sq * invE + 1e-3f);
  const float4 g = *(const float4*)(gamma + tid * 4);
  const float4 be = *(const float4*)(beta + tid * 4);
  float4 o;
  o.x = g.x * d[0] * rs + be.x;
  o.y = g.y * d[1] * rs + be.y;
  o.z = g.z * d[2] * rs + be.z;
  o.w = g.w * d[3] * rs + be.w;
  if (RELU_OUT) {
    o.x = fmaxf(o.x, 0.f);
    o.y = fmaxf(o.y, 0.f);
    o.z = fmaxf(o.z, 0.f);
    o.w = fmaxf(o.w, 0.f);
  }
  *(float4*)(out + r * (long long)E + tid * 4) = o;
}

extern "C" void kernel_launch(void* const* d_in, const int* in_sizes, int n_in,
                              void* d_out, int out_size, void* d_ws,
                              size_t ws_size, hipStream_t stream) {
  const int B = 8, S = 2048, E = 1024;
  const int M = B * S;  // 16384

  const float* inputs = (const float*)d_in[0];
  const float* context = (const float*)d_in[1];
  const float* Wq = (const float*)d_in[2];
  const float* Wk = (const float*)d_in[3];
  const float* Wv = (const float*)d_in[4];
  const float* Wcq = (const float*)d_in[5];
  const float* Wck = (const float*)d_in[6];
  const float* Wcv = (const float*)d_in[7];
  const float* gamma = (const float*)d_in[8];
  const float* beta = (const float*)d_in[9];
  const float* W1 = (const float*)d_in[10];
  const float* b1 = (const float*)d_in[11];
  float* out = (float*)d_out;

  char* wsb = (char*)d_ws;
  const size_t BUF = (size_t)B * S * E * sizeof(float);  // 64 MB
  float* t0 = (float*)(wsb);
  float* t1 = (float*)(wsb + BUF);
  float* t2 = (float*)(wsb + 2 * BUF);
  float* sc = (float*)(wsb + 3 * BUF);

  // Adaptive q-chunk: largest of {512,256,128,64} whose score buffer fits ws.
  int qc = 512;
  while (qc > 64 &&
         3 * BUF + (size_t)B * qc * S * sizeof(float) > ws_size)
    qc >>= 1;
  const int nchunks = S / qc;

  const long long sSE = (long long)S * E;
  const long long sCS = (long long)qc * S;  // per-batch stride in sc
  const float sscale = 0.03125f;  // 1/sqrt(1024)

  dim3 blk(256);
  dim3 gProj(E / TN, M / TM, 1);        // (8,128,1)
  dim3 gScore(S / TN, qc / TM > 0 ? qc / TM : 1, B);
  dim3 gPV(E / TN, qc / TM > 0 ? qc / TM : 1, B);
  dim3 gRowChunk(B * qc);
  dim3 gRow(B * S);

  // For qc=64 the TM=128 tile still works only if qc>=TM; clamp qc to >=128
  // by accepting overflow risk only in the impossible case ws < 200MB.
  if (qc < TM) qc = TM;

  // --- self-attention projections ---
  gemm_nn<false, false, false><<<gProj, blk, 0, stream>>>(
      inputs, Wq, t0, nullptr, E, E, 0, 0, 0, 1.0f, 0);
  gemm_nn<false, false, false><<<gProj, blk, 0, stream>>>(
      inputs, Wk, t1, nullptr, E, E, 0, 0, 0, 1.0f, 0);
  gemm_nn<false, false, false><<<gProj, blk, 0, stream>>>(
      inputs, Wv, t2, nullptr, E, E, 0, 0, 0, 1.0f, 0);

  // --- self-attention, chunked over q; O overwrites Q chunk in t0 ---
  for (int c = 0; c < nchunks; ++c) {
    const int mofs = c * qc;
    gemm_nt<true><<<gScore, blk, 0, stream>>>(
        t0 + (long long)mofs * E, t1, sc, S, E, sSE, sSE, sCS, sscale, mofs);
    softmax_rows<<<gRowChunk, blk, 0, stream>>>(sc, S, qc, 1, mofs);
    gemm_nn<false, false, true><<<gPV, blk, 0, stream>>>(
        sc, t2, t0 + (long long)mofs * E, nullptr, E, S, sCS, sSE, sSE, 1.0f,
        mofs);
  }
  // h = LN(O + inputs) -> t0 (in place)
  add_ln<false><<<gRow, blk, 0, stream>>>(t0, inputs, gamma, beta, t0, E);

  // --- cross-attention projections ---
  gemm_nn<false, false, false><<<gProj, blk, 0, stream>>>(
      t0, Wcq, t1, nullptr, E, E, 0, 0, 0, 1.0f, 0);
  gemm_nn<false, false, false><<<gProj, blk, 0, stream>>>(
      context, Wck, t2, nullptr, E, E, 0, 0, 0, 1.0f, 0);
  gemm_nn<false, false, false><<<gProj, blk, 0, stream>>>(
      context, Wcv, out, nullptr, E, E, 0, 0, 0, 1.0f, 0);  // V2 in d_out

  // --- cross-attention, chunked; O2 overwrites Q2 chunk in t1 ---
  for (int c = 0; c < nchunks; ++c) {
    const int mofs = c * qc;
    gemm_nt<false><<<gScore, blk, 0, stream>>>(
        t1 + (long long)mofs * E, t2, sc, S, E, sSE, sSE, sCS, sscale, mofs);
    softmax_rows<<<gRowChunk, blk, 0, stream>>>(sc, S, qc, 0, mofs);
    gemm_nn<false, false, false><<<gPV, blk, 0, stream>>>(
        sc, out, t1 + (long long)mofs * E, nullptr, E, S, sCS, sSE, sSE, 1.0f,
        0);
  }
  // h2 = LN(O2 + h) -> t1 (in place)
  add_ln<false><<<gRow, blk, 0, stream>>>(t1, t0, gamma, beta, t1, E);

  // --- FFN ---
  gemm_nn<true, true, false><<<gProj, blk, 0, stream>>>(
      t1, W1, t2, b1, E, E, 0, 0, 0, 1.0f, 0);  // f = relu(h2@W1+b1)
  add_ln<true><<<gRow, blk, 0, stream>>>(t2, t1, gamma, beta, out, E);
}

// Round 4
// 2888.250 us; speedup vs baseline: 2.6109x; 2.6109x over previous
//
#include <hip/hip_runtime.h>
#include <math.h>

// ---------------------------------------------------------------------------
// Transformer block (B=8, S=2048, E=1024) — split-bf16 MFMA version.
// Every fp32 tensor value is packed into one u32: bits[15:0] = bf16(trunc) hi,
// bits[31:16] = bf16 of residual lo (value ~= hi + lo, ~2^-16 rel precision).
// GEMMs run on mfma_f32_16x16x32_bf16 with 3 passes: Ah*Bh + Al*Bh + Ah*Bl.
//
// Buffers (u32-packed unless noted):
//  s1: Q -> O(in-place/chunk) -> h(in-place) -> h2(in-place)
//  s2: K -> Q2 -> O2(in-place/chunk) -> f
//  s3: Vt -> K2
//  d_out: V2t (scratch) -> final fp32 output
//  wt: 7 transpose-packed weights (28MB); sc: fp32 scores -> packed P in-place
// ---------------------------------------------------------------------------

typedef unsigned int u32;
typedef __attribute__((ext_vector_type(8))) short short8;
typedef __attribute__((ext_vector_type(4))) float f32x4;

__device__ __forceinline__ u32 packhl(float x) {
  u32 u = __float_as_uint(x);
  float hf = __uint_as_float(u & 0xFFFF0000u);   // truncated-bf16 hi
  u32 lu = __float_as_uint(x - hf);              // exact residual (Sterbenz)
  return (u >> 16) | (lu & 0xFFFF0000u);
}
__device__ __forceinline__ float unpackhl(u32 p) {
  return __uint_as_float(p << 16) + __uint_as_float(p & 0xFFFF0000u);
}

__device__ __forceinline__ float wave_reduce_sum(float v) {
#pragma unroll
  for (int m = 32; m >= 1; m >>= 1) v += __shfl_xor(v, m, 64);
  return v;
}
__device__ __forceinline__ float wave_reduce_max(float v) {
#pragma unroll
  for (int m = 32; m >= 1; m >>= 1) v = fmaxf(v, __shfl_xor(v, m, 64));
  return v;
}
__device__ __forceinline__ float block_reduce_sum(float v, float* red) {
  v = wave_reduce_sum(v);
  if ((threadIdx.x & 63) == 0) red[threadIdx.x >> 6] = v;
  __syncthreads();
  const float r = red[0] + red[1] + red[2] + red[3];
  __syncthreads();
  return r;
}
__device__ __forceinline__ float block_reduce_max(float v, float* red) {
  v = wave_reduce_max(v);
  if ((threadIdx.x & 63) == 0) red[threadIdx.x >> 6] = v;
  __syncthreads();
  const float r = fmaxf(fmaxf(red[0], red[1]), fmaxf(red[2], red[3]));
  __syncthreads();
  return r;
}

// ---------------------------------------------------------------------------
// gemm_hl: C[b] = alpha * A[b] (MxK) * Bt[b] (NxK)^T   (both K-contiguous)
// A: packed u32 if APACK, else fp32 (converted during staging).
// Bt: always packed u32.
// EPI: 0 = fp32 out *alpha (scores); 1 = packed out; 2 = packed TRANSPOSED out
//      (V-proj: out[b][col][row], per-batch rows = 2048); 3 = packed bias+relu.
// CAUSAL: skip blocks fully above diagonal (global row = mofs + local row).
// KCAP: K limited to mofs + m0 + 128 (causal PV).
// ---------------------------------------------------------------------------
template <bool APACK, int EPI, bool CAUSAL, bool KCAP>
__global__ __launch_bounds__(256) void gemm_hl(
    const void* __restrict__ A_, const u32* __restrict__ Bt,
    void* __restrict__ C_, const float* __restrict__ bias,
    int N, int K, long long sA, long long sB, long long sC,
    float alpha, int mofs) {
  const int b = blockIdx.z;
  const int m0 = blockIdx.y * 128;
  const int n0 = blockIdx.x * 128;
  if (CAUSAL && n0 >= mofs + m0 + 128) return;
  const u32* Ap = (const u32*)A_ + (long long)b * sA;
  const float* Af = (const float*)A_ + (long long)b * sA;
  const u32* Bp = Bt + (long long)b * sB;
  int Keff = K;
  if (KCAP) {
    int ke = mofs + m0 + 128;
    Keff = ke < K ? ke : K;
  }

  __shared__ u32 As[4096];  // [128][32] packed, XOR-swizzled
  __shared__ u32 Bs[4096];

  const int t = threadIdx.x;
  const int lane = t & 63, wv = t >> 6;
  const int wr = wv >> 1, wc = wv & 1;
  const int lr = lane & 15, kg = lane >> 4;
  const int srow = t >> 1;           // staging row 0..127
  const int skh = (t & 1) << 4;      // k offset 0/16

  f32x4 acc[4][4];
#pragma unroll
  for (int i = 0; i < 4; ++i)
#pragma unroll
    for (int j = 0; j < 4; ++j) {
      acc[i][j][0] = 0.f; acc[i][j][1] = 0.f;
      acc[i][j][2] = 0.f; acc[i][j][3] = 0.f;
    }

  for (int k0 = 0; k0 < Keff; k0 += 32) {
    // ---- stage A tile [128][32] ----
    {
      const long long abase = (long long)(m0 + srow) * K + k0 + skh;
#pragma unroll
      for (int u = 0; u < 4; ++u) {
        uint4 w;
        if (APACK) {
          w = *(const uint4*)(Ap + abase + 4 * u);
        } else {
          const float4 f = *(const float4*)(Af + abase + 4 * u);
          w.x = packhl(f.x); w.y = packhl(f.y);
          w.z = packhl(f.z); w.w = packhl(f.w);
        }
        const int dw = (srow * 32 + skh + 4 * u) ^ ((srow & 7) << 2);
        *(uint4*)&As[dw] = w;
      }
      const long long bbase = (long long)(n0 + srow) * K + k0 + skh;
#pragma unroll
      for (int u = 0; u < 4; ++u) {
        uint4 w = *(const uint4*)(Bp + bbase + 4 * u);
        const int dw = (srow * 32 + skh + 4 * u) ^ ((srow & 7) << 2);
        *(uint4*)&Bs[dw] = w;
      }
    }
    __syncthreads();

    // ---- fragments ----
    short8 ah[4], al[4], bh[4], bl[4];
#pragma unroll
    for (int mf = 0; mf < 4; ++mf) {
      const int row = wr * 64 + mf * 16 + lr;
      const int base = row * 32 + kg * 8;
      const int sw = (row & 7) << 2;
      const uint4 p0 = *(const uint4*)&As[base ^ sw];
      const uint4 p1 = *(const uint4*)&As[(base + 4) ^ sw];
      union { u32 u[4]; short8 s; } H, L;
      H.u[0] = (p0.x & 0xFFFFu) | (p0.y << 16);
      H.u[1] = (p0.z & 0xFFFFu) | (p0.w << 16);
      H.u[2] = (p1.x & 0xFFFFu) | (p1.y << 16);
      H.u[3] = (p1.z & 0xFFFFu) | (p1.w << 16);
      L.u[0] = (p0.x >> 16) | (p0.y & 0xFFFF0000u);
      L.u[1] = (p0.z >> 16) | (p0.w & 0xFFFF0000u);
      L.u[2] = (p1.x >> 16) | (p1.y & 0xFFFF0000u);
      L.u[3] = (p1.z >> 16) | (p1.w & 0xFFFF0000u);
      ah[mf] = H.s; al[mf] = L.s;
    }
#pragma unroll
    for (int nf = 0; nf < 4; ++nf) {
      const int row = wc * 64 + nf * 16 + lr;
      const int base = row * 32 + kg * 8;
      const int sw = (row & 7) << 2;
      const uint4 p0 = *(const uint4*)&Bs[base ^ sw];
      const uint4 p1 = *(const uint4*)&Bs[(base + 4) ^ sw];
      union { u32 u[4]; short8 s; } H, L;
      H.u[0] = (p0.x & 0xFFFFu) | (p0.y << 16);
      H.u[1] = (p0.z & 0xFFFFu) | (p0.w << 16);
      H.u[2] = (p1.x & 0xFFFFu) | (p1.y << 16);
      H.u[3] = (p1.z & 0xFFFFu) | (p1.w << 16);
      L.u[0] = (p0.x >> 16) | (p0.y & 0xFFFF0000u);
      L.u[1] = (p0.z >> 16) | (p0.w & 0xFFFF0000u);
      L.u[2] = (p1.x >> 16) | (p1.y & 0xFFFF0000u);
      L.u[3] = (p1.z >> 16) | (p1.w & 0xFFFF0000u);
      bh[nf] = H.s; bl[nf] = L.s;
    }
#pragma unroll
    for (int nf = 0; nf < 4; ++nf)
#pragma unroll
      for (int mf = 0; mf < 4; ++mf) {
        acc[mf][nf] = __builtin_amdgcn_mfma_f32_16x16x32_bf16(
            ah[mf], bh[nf], acc[mf][nf], 0, 0, 0);
        acc[mf][nf] = __builtin_amdgcn_mfma_f32_16x16x32_bf16(
            al[mf], bh[nf], acc[mf][nf], 0, 0, 0);
        acc[mf][nf] = __builtin_amdgcn_mfma_f32_16x16x32_bf16(
            ah[mf], bl[nf], acc[mf][nf], 0, 0, 0);
      }
    __syncthreads();
  }

  // ---- epilogue ----
  if (EPI == 2) {
    // transposed packed: out[b][col][row] with per-batch 2048 rows
    u32* Ct = (u32*)C_;
#pragma unroll
    for (int mf = 0; mf < 4; ++mf)
#pragma unroll
      for (int nf = 0; nf < 4; ++nf) {
        const int gr = m0 + wr * 64 + mf * 16 + (lane >> 4) * 4;
        const int gc = n0 + wc * 64 + nf * 16 + lr;
        const int bb = gr >> 11, ss = gr & 2047;
        uint4 o;
        o.x = packhl(acc[mf][nf][0]); o.y = packhl(acc[mf][nf][1]);
        o.z = packhl(acc[mf][nf][2]); o.w = packhl(acc[mf][nf][3]);
        *(uint4*)(Ct + (long long)bb * N * 2048 + (long long)gc * 2048 + ss) = o;
      }
  } else {
    const long long cb = (long long)b * sC;
#pragma unroll
    for (int mf = 0; mf < 4; ++mf)
#pragma unroll
      for (int nf = 0; nf < 4; ++nf) {
        const int gr0 = m0 + wr * 64 + mf * 16 + (lane >> 4) * 4;
        const int gc = n0 + wc * 64 + nf * 16 + lr;
#pragma unroll
        for (int i = 0; i < 4; ++i) {
          float v = acc[mf][nf][i] * alpha;
          if (EPI == 3) { v += bias[gc]; v = fmaxf(v, 0.f); }
          if (EPI == 0)
            *((float*)C_ + cb + (long long)(gr0 + i) * N + gc) = v;
          else
            *((u32*)C_ + cb + (long long)(gr0 + i) * N + gc) = packhl(v);
        }
      }
  }
}

// ---------------------------------------------------------------------------
// Row softmax over ncols=2048 fp32; writes PACKED u32 in place.
// ---------------------------------------------------------------------------
__global__ __launch_bounds__(256) void softmax_rows(
    float* __restrict__ S_, int ncols, int qcc, int causal, int qofs) {
  __shared__ float red[4];
  const long long r = blockIdx.x;
  const int q = qofs + (int)(r % qcc);
  float* row = S_ + r * (long long)ncols;
  const int tid = threadIdx.x;
  float v[8];
  *(float4*)&v[0] = *(const float4*)(row + tid * 8);
  *(float4*)&v[4] = *(const float4*)(row + tid * 8 + 4);
  if (causal) {
#pragma unroll
    for (int j = 0; j < 8; ++j)
      if (tid * 8 + j > q) v[j] = -INFINITY;
  }
  float m = -INFINITY;
#pragma unroll
  for (int j = 0; j < 8; ++j) m = fmaxf(m, v[j]);
  m = block_reduce_max(m, red);
  float s = 0.f;
#pragma unroll
  for (int j = 0; j < 8; ++j) {
    v[j] = __expf(v[j] - m);
    s += v[j];
  }
  s = block_reduce_sum(s, red);
  const float inv = 1.0f / s;
  u32* rowp = (u32*)row;
  uint4 o0, o1;
  o0.x = packhl(v[0] * inv); o0.y = packhl(v[1] * inv);
  o0.z = packhl(v[2] * inv); o0.w = packhl(v[3] * inv);
  o1.x = packhl(v[4] * inv); o1.y = packhl(v[5] * inv);
  o1.z = packhl(v[6] * inv); o1.w = packhl(v[7] * inv);
  *(uint4*)(rowp + tid * 8) = o0;
  *(uint4*)(rowp + tid * 8 + 4) = o1;
}

// ---------------------------------------------------------------------------
// add_ln: out[r] = (relu?) LN(X[r] + Y[r]).  X/Y packed or fp32; out packed or
// fp32. In-place safe (row-private). E=1024, 256 threads x 4 elems.
// ---------------------------------------------------------------------------
template <bool XP, bool YP, bool OUTP, bool RELU>
__global__ __launch_bounds__(256) void add_ln(
    const void* __restrict__ X_, const void* __restrict__ Y_,
    const float* __restrict__ gamma, const float* __restrict__ beta,
    void* __restrict__ out_, int E) {
  __shared__ float red[4];
  const long long r = blockIdx.x;
  const int tid = threadIdx.x;
  const float invE = 1.0f / (float)E;
  float v[4];
  if (XP) {
    const uint4 a = *(const uint4*)((const u32*)X_ + r * E + tid * 4);
    v[0] = unpackhl(a.x); v[1] = unpackhl(a.y);
    v[2] = unpackhl(a.z); v[3] = unpackhl(a.w);
  } else {
    const float4 a = *(const float4*)((const float*)X_ + r * E + tid * 4);
    v[0] = a.x; v[1] = a.y; v[2] = a.z; v[3] = a.w;
  }
  if (YP) {
    const uint4 bq = *(const uint4*)((const u32*)Y_ + r * E + tid * 4);
    v[0] += unpackhl(bq.x); v[1] += unpackhl(bq.y);
    v[2] += unpackhl(bq.z); v[3] += unpackhl(bq.w);
  } else {
    const float4 bq = *(const float4*)((const float*)Y_ + r * E + tid * 4);
    v[0] += bq.x; v[1] += bq.y; v[2] += bq.z; v[3] += bq.w;
  }
  float s = v[0] + v[1] + v[2] + v[3];
  s = block_reduce_sum(s, red);
  const float mu = s * invE;
  float d[4], sq = 0.f;
#pragma unroll
  for (int j = 0; j < 4; ++j) {
    d[j] = v[j] - mu;
    sq += d[j] * d[j];
  }
  sq = block_reduce_sum(sq, red);
  const float rs = rsqrtf(sq * invE + 1e-3f);
  const float4 g = *(const float4*)(gamma + tid * 4);
  const float4 be = *(const float4*)(beta + tid * 4);
  float o[4];
  o[0] = g.x * d[0] * rs + be.x; o[1] = g.y * d[1] * rs + be.y;
  o[2] = g.z * d[2] * rs + be.z; o[3] = g.w * d[3] * rs + be.w;
  if (RELU) {
#pragma unroll
    for (int j = 0; j < 4; ++j) o[j] = fmaxf(o[j], 0.f);
  }
  if (OUTP) {
    uint4 w;
    w.x = packhl(o[0]); w.y = packhl(o[1]);
    w.z = packhl(o[2]); w.w = packhl(o[3]);
    *(uint4*)((u32*)out_ + r * E + tid * 4) = w;
  } else {
    float4 w;
    w.x = o[0]; w.y = o[1]; w.z = o[2]; w.w = o[3];
    *(float4*)((float*)out_ + r * E + tid * 4) = w;
  }
}

// ---------------------------------------------------------------------------
// Weight transpose+pack: W[1024][1024] fp32 -> out[widx][n][k] packed u32.
// ---------------------------------------------------------------------------
__global__ __launch_bounds__(256) void wpack_t(
    const float* __restrict__ W0, const float* __restrict__ W1_,
    const float* __restrict__ W2, const float* __restrict__ W3,
    const float* __restrict__ W4, const float* __restrict__ W5,
    const float* __restrict__ W6, u32* __restrict__ out) {
  __shared__ float tile[64][65];
  const int wi = blockIdx.z;
  const float* W = wi == 0 ? W0 : wi == 1 ? W1_ : wi == 2 ? W2
                 : wi == 3 ? W3 : wi == 4 ? W4 : wi == 5 ? W5 : W6;
  const int k0 = blockIdx.y * 64, n0 = blockIdx.x * 64;
  const int tr = threadIdx.x >> 4, tc4 = (threadIdx.x & 15) * 4;
#pragma unroll
  for (int i = 0; i < 4; ++i) {
    const int row = tr * 4 + i;
    const float4 v = *(const float4*)(W + (long long)(k0 + row) * 1024 + n0 + tc4);
    tile[row][tc4 + 0] = v.x; tile[row][tc4 + 1] = v.y;
    tile[row][tc4 + 2] = v.z; tile[row][tc4 + 3] = v.w;
  }
  __syncthreads();
  u32* o = out + (long long)wi * 1048576;
#pragma unroll
  for (int i = 0; i < 4; ++i) {
    const int nrow = tr * 4 + i;
    uint4 w;
    w.x = packhl(tile[tc4 + 0][nrow]);
    w.y = packhl(tile[tc4 + 1][nrow]);
    w.z = packhl(tile[tc4 + 2][nrow]);
    w.w = packhl(tile[tc4 + 3][nrow]);
    *(uint4*)(o + (long long)(n0 + nrow) * 1024 + k0 + tc4) = w;
  }
}

extern "C" void kernel_launch(void* const* d_in, const int* in_sizes, int n_in,
                              void* d_out, int out_size, void* d_ws,
                              size_t ws_size, hipStream_t stream) {
  const int B = 8, S = 2048, E = 1024;
  const int M = B * S;

  const float* inputs = (const float*)d_in[0];
  const float* context = (const float*)d_in[1];
  const float* Wq = (const float*)d_in[2];
  const float* Wk = (const float*)d_in[3];
  const float* Wv = (const float*)d_in[4];
  const float* Wcq = (const float*)d_in[5];
  const float* Wck = (const float*)d_in[6];
  const float* Wcv = (const float*)d_in[7];
  const float* gamma = (const float*)d_in[8];
  const float* beta = (const float*)d_in[9];
  const float* W1 = (const float*)d_in[10];
  const float* b1 = (const float*)d_in[11];
  float* out = (float*)d_out;

  char* wsb = (char*)d_ws;
  const size_t BUF = (size_t)M * E * 4;  // 64 MB
  u32* s1 = (u32*)wsb;
  u32* s2 = (u32*)(wsb + BUF);
  u32* s3 = (u32*)(wsb + 2 * BUF);
  u32* wt = (u32*)(wsb + 3 * BUF);
  const size_t WTB = (size_t)7 * 1024 * 1024 * 4;  // 28 MB
  float* sc = (float*)(wsb + 3 * BUF + WTB);

  int qc = 512;
  while (qc > 128 && 3 * BUF + WTB + (size_t)B * qc * S * 4 > ws_size) qc >>= 1;
  const int nchunks = S / qc;

  const long long sSE = (long long)S * E;
  const long long sCS = (long long)qc * S;
  const long long sES = (long long)E * S;
  const float sscale = 0.03125f;

  dim3 blk(256);
  dim3 gProj(8, 128, 1);
  dim3 gScore(16, qc / 128, B);
  dim3 gPV(8, qc / 128, B);
  dim3 gRowC(B * qc);
  dim3 gRow(M);

  // weights: transpose + pack
  wpack_t<<<dim3(16, 16, 7), blk, 0, stream>>>(Wq, Wk, Wv, Wcq, Wck, Wcv, W1, wt);
  const u32* WqT = wt;
  const u32* WkT = wt + 1 * 1048576;
  const u32* WvT = wt + 2 * 1048576;
  const u32* WcqT = wt + 3 * 1048576;
  const u32* WckT = wt + 4 * 1048576;
  const u32* WcvT = wt + 5 * 1048576;
  const u32* W1T = wt + 6 * 1048576;

  // --- self-attention projections (A = inputs fp32) ---
  gemm_hl<false, 1, false, false><<<gProj, blk, 0, stream>>>(
      inputs, WqT, s1, nullptr, E, E, 0, 0, 0, 1.f, 0);
  gemm_hl<false, 1, false, false><<<gProj, blk, 0, stream>>>(
      inputs, WkT, s2, nullptr, E, E, 0, 0, 0, 1.f, 0);
  gemm_hl<false, 2, false, false><<<gProj, blk, 0, stream>>>(
      inputs, WvT, s3, nullptr, E, E, 0, 0, 0, 1.f, 0);  // Vt packed

  // --- self-attention (causal), chunked; O overwrites Q chunk ---
  for (int c = 0; c < nchunks; ++c) {
    const int mofs = c * qc;
    gemm_hl<true, 0, true, false><<<gScore, blk, 0, stream>>>(
        s1 + (long long)mofs * E, s2, sc, nullptr, S, E, sSE, sSE, sCS,
        sscale, mofs);
    softmax_rows<<<gRowC, blk, 0, stream>>>(sc, S, qc, 1, mofs);
    gemm_hl<true, 1, false, true><<<gPV, blk, 0, stream>>>(
        sc, s3, s1 + (long long)mofs * E, nullptr, E, S, sCS, sES, sSE,
        1.f, mofs);
  }
  // h = LN(O + inputs) -> s1 packed (in place)
  add_ln<true, false, true, false><<<gRow, blk, 0, stream>>>(
      s1, inputs, gamma, beta, s1, E);

  // --- cross projections ---
  gemm_hl<true, 1, false, false><<<gProj, blk, 0, stream>>>(
      s1, WcqT, s2, nullptr, E, E, 0, 0, 0, 1.f, 0);  // Q2
  gemm_hl<false, 1, false, false><<<gProj, blk, 0, stream>>>(
      context, WckT, s3, nullptr, E, E, 0, 0, 0, 1.f, 0);  // K2
  gemm_hl<false, 2, false, false><<<gProj, blk, 0, stream>>>(
      context, WcvT, d_out, nullptr, E, E, 0, 0, 0, 1.f, 0);  // V2t in d_out

  // --- cross-attention, chunked; O2 overwrites Q2 chunk ---
  for (int c = 0; c < nchunks; ++c) {
    const int mofs = c * qc;
    gemm_hl<true, 0, false, false><<<gScore, blk, 0, stream>>>(
        s2 + (long long)mofs * E, s3, sc, nullptr, S, E, sSE, sSE, sCS,
        sscale, 0);
    softmax_rows<<<gRowC, blk, 0, stream>>>(sc, S, qc, 0, mofs);
    gemm_hl<true, 1, false, false><<<gPV, blk, 0, stream>>>(
        sc, (const u32*)d_out, s2 + (long long)mofs * E, nullptr, E, S, sCS,
        sES, sSE, 1.f, 0);
  }
  // h2 = LN(O2 + h) -> s1 packed (in place over h)
  add_ln<true, true, true, false><<<gRow, blk, 0, stream>>>(
      s2, s1, gamma, beta, s1, E);

  // --- FFN: f = relu(h2 @ W1 + b1) -> s2 packed ---
  gemm_hl<true, 3, false, false><<<gProj, blk, 0, stream>>>(
      s1, W1T, s2, b1, E, E, 0, 0, 0, 1.f, 0);

  // out = relu(LN(f + h2)) -> d_out fp32
  add_ln<true, true, false, true><<<gRow, blk, 0, stream>>>(
      s2, s1, gamma, beta, out, E);
}

// Round 10
// 2429.384 us; speedup vs baseline: 3.1040x; 1.1889x over previous
//
#include <hip/hip_runtime.h>
#include <math.h>

// ---------------------------------------------------------------------------
// Transformer block (B=8, S=2048, E=1024) — split-bf16 MFMA, plane-split LDS.
// Packed u32 format in global: bits[15:0]=bf16 hi (trunc), bits[31:16]=bf16 of
// residual lo.  GEMM: C ~= Ah*Bh + Al*Bh + Ah*Bl (3 MFMA passes).
// This round: LDS stores hi/lo as SEPARATE bf16 planes (split once at staging,
// compute phase is pure ds_read_b128+MFMA) + 2-phase reg-staged prefetch.
// ---------------------------------------------------------------------------

typedef unsigned int u32;
typedef __attribute__((ext_vector_type(8))) short short8;
typedef __attribute__((ext_vector_type(4))) float f32x4;

__device__ __forceinline__ u32 packhl(float x) {
  u32 u = __float_as_uint(x);
  float hf = __uint_as_float(u & 0xFFFF0000u);   // truncated-bf16 hi
  u32 lu = __float_as_uint(x - hf);              // exact residual
  return (u >> 16) | (lu & 0xFFFF0000u);
}
__device__ __forceinline__ float unpackhl(u32 p) {
  return __uint_as_float(p << 16) + __uint_as_float(p & 0xFFFF0000u);
}

__device__ __forceinline__ float wave_reduce_sum(float v) {
#pragma unroll
  for (int m = 32; m >= 1; m >>= 1) v += __shfl_xor(v, m, 64);
  return v;
}
__device__ __forceinline__ float wave_reduce_max(float v) {
#pragma unroll
  for (int m = 32; m >= 1; m >>= 1) v = fmaxf(v, __shfl_xor(v, m, 64));
  return v;
}
__device__ __forceinline__ float block_reduce_sum(float v, float* red) {
  v = wave_reduce_sum(v);
  if ((threadIdx.x & 63) == 0) red[threadIdx.x >> 6] = v;
  __syncthreads();
  const float r = red[0] + red[1] + red[2] + red[3];
  __syncthreads();
  return r;
}
__device__ __forceinline__ float block_reduce_max(float v, float* red) {
  v = wave_reduce_max(v);
  if ((threadIdx.x & 63) == 0) red[threadIdx.x >> 6] = v;
  __syncthreads();
  const float r = fmaxf(fmaxf(red[0], red[1]), fmaxf(red[2], red[3]));
  __syncthreads();
  return r;
}

#define LROW 20  // u32 words per LDS plane row (40 bf16 = 80 B; 32 used + pad)

// ---------------------------------------------------------------------------
// gemm_hl: C[b] = alpha * A[b](MxK) * Bt[b](NxK)^T, K-contiguous operands.
// A packed u32 if APACK else fp32 (split during staging). Bt packed u32.
// EPI: 0 fp32*alpha out; 1 packed out; 2 packed transposed out; 3 bias+relu.
// ---------------------------------------------------------------------------
template <bool APACK, int EPI, bool CAUSAL, bool KCAP>
__global__ __launch_bounds__(256) void gemm_hl(
    const void* __restrict__ A_, const u32* __restrict__ Bt,
    void* __restrict__ C_, const float* __restrict__ bias,
    int N, int K, long long sA, long long sB, long long sC,
    float alpha, int mofs) {
  const int b = blockIdx.z;
  const int m0 = blockIdx.y * 128;
  const int n0 = blockIdx.x * 128;
  if (CAUSAL && n0 >= mofs + m0 + 128) return;
  const u32* Ap = (const u32*)A_ + (long long)b * sA;
  const float* Af = (const float*)A_ + (long long)b * sA;
  const u32* Bp = Bt + (long long)b * sB;
  int Keff = K;
  if (KCAP) {
    int ke = mofs + m0 + 128;
    Keff = ke < K ? ke : K;
  }
  const int nt = Keff >> 5;  // K-steps of 32

  // 4 bf16 planes [128][40] (80 B rows): Ah, Al, Bh, Bl  -> 40 KiB total
  __shared__ u32 Ah_s[128 * LROW];
  __shared__ u32 Al_s[128 * LROW];
  __shared__ u32 Bh_s[128 * LROW];
  __shared__ u32 Bl_s[128 * LROW];

  const int t = threadIdx.x;
  const int lane = t & 63, wv = t >> 6;
  const int wr = wv >> 1, wc = wv & 1;
  const int lr = lane & 15, kg = lane >> 4;
  const int srow = t >> 1;        // staging row 0..127
  const int skh = (t & 1) << 4;   // K offset 0/16 within tile
  const int swidx = srow * LROW + (skh >> 1);  // u32 idx of this thread's 32B

  f32x4 acc[4][4];
#pragma unroll
  for (int i = 0; i < 4; ++i)
#pragma unroll
    for (int j = 0; j < 4; ++j) {
      acc[i][j][0] = 0.f; acc[i][j][1] = 0.f;
      acc[i][j][2] = 0.f; acc[i][j][3] = 0.f;
    }

  // in-flight tile registers (16 K-elements each for A and B)
  uint4 ga0, ga1, ga2, ga3, gb0, gb1, gb2, gb3;
  float4 fa0, fa1, fa2, fa3;

  const long long arow = (long long)(m0 + srow) * K + skh;
  const long long brow = (long long)(n0 + srow) * K + skh;

#define LOADT(k0)                                                   \
  do {                                                              \
    if (APACK) {                                                    \
      ga0 = *(const uint4*)(Ap + arow + (k0));                      \
      ga1 = *(const uint4*)(Ap + arow + (k0) + 4);                  \
      ga2 = *(const uint4*)(Ap + arow + (k0) + 8);                  \
      ga3 = *(const uint4*)(Ap + arow + (k0) + 12);                 \
    } else {                                                        \
      fa0 = *(const float4*)(Af + arow + (k0));                     \
      fa1 = *(const float4*)(Af + arow + (k0) + 4);                 \
      fa2 = *(const float4*)(Af + arow + (k0) + 8);                 \
      fa3 = *(const float4*)(Af + arow + (k0) + 12);                \
    }                                                               \
    gb0 = *(const uint4*)(Bp + brow + (k0));                        \
    gb1 = *(const uint4*)(Bp + brow + (k0) + 4);                    \
    gb2 = *(const uint4*)(Bp + brow + (k0) + 8);                    \
    gb3 = *(const uint4*)(Bp + brow + (k0) + 12);                   \
  } while (0)

  // split packed pair (p0=elem k, p1=elem k+1) -> hi word / lo word
#define HISPLIT(p0, p1) (((p0) & 0xFFFFu) | ((p1) << 16))
#define LOSPLIT(p0, p1) (((p0) >> 16) | ((p1) & 0xFFFF0000u))

  LOADT(0);

  for (int tt = 0; tt < nt; ++tt) {
    // ---- split in-flight regs into hi/lo planes ----
    uint4 h, l;
    if (APACK) {
      h.x = HISPLIT(ga0.x, ga0.y); h.y = HISPLIT(ga0.z, ga0.w);
      h.z = HISPLIT(ga1.x, ga1.y); h.w = HISPLIT(ga1.z, ga1.w);
      l.x = LOSPLIT(ga0.x, ga0.y); l.y = LOSPLIT(ga0.z, ga0.w);
      l.z = LOSPLIT(ga1.x, ga1.y); l.w = LOSPLIT(ga1.z, ga1.w);
      *(uint4*)&Ah_s[swidx] = h; *(uint4*)&Al_s[swidx] = l;
      h.x = HISPLIT(ga2.x, ga2.y); h.y = HISPLIT(ga2.z, ga2.w);
      h.z = HISPLIT(ga3.x, ga3.y); h.w = HISPLIT(ga3.z, ga3.w);
      l.x = LOSPLIT(ga2.x, ga2.y); l.y = LOSPLIT(ga2.z, ga2.w);
      l.z = LOSPLIT(ga3.x, ga3.y); l.w = LOSPLIT(ga3.z, ga3.w);
      *(uint4*)&Ah_s[swidx + 4] = h; *(uint4*)&Al_s[swidx + 4] = l;
    } else {
      u32 pk[16];
      pk[0] = packhl(fa0.x); pk[1] = packhl(fa0.y);
      pk[2] = packhl(fa0.z); pk[3] = packhl(fa0.w);
      pk[4] = packhl(fa1.x); pk[5] = packhl(fa1.y);
      pk[6] = packhl(fa1.z); pk[7] = packhl(fa1.w);
      pk[8] = packhl(fa2.x); pk[9] = packhl(fa2.y);
      pk[10] = packhl(fa2.z); pk[11] = packhl(fa2.w);
      pk[12] = packhl(fa3.x); pk[13] = packhl(fa3.y);
      pk[14] = packhl(fa3.z); pk[15] = packhl(fa3.w);
      h.x = HISPLIT(pk[0], pk[1]); h.y = HISPLIT(pk[2], pk[3]);
      h.z = HISPLIT(pk[4], pk[5]); h.w = HISPLIT(pk[6], pk[7]);
      l.x = LOSPLIT(pk[0], pk[1]); l.y = LOSPLIT(pk[2], pk[3]);
      l.z = LOSPLIT(pk[4], pk[5]); l.w = LOSPLIT(pk[6], pk[7]);
      *(uint4*)&Ah_s[swidx] = h; *(uint4*)&Al_s[swidx] = l;
      h.x = HISPLIT(pk[8], pk[9]); h.y = HISPLIT(pk[10], pk[11]);
      h.z = HISPLIT(pk[12], pk[13]); h.w = HISPLIT(pk[14], pk[15]);
      l.x = LOSPLIT(pk[8], pk[9]); l.y = LOSPLIT(pk[10], pk[11]);
      l.z = LOSPLIT(pk[12], pk[13]); l.w = LOSPLIT(pk[14], pk[15]);
      *(uint4*)&Ah_s[swidx + 4] = h; *(uint4*)&Al_s[swidx + 4] = l;
    }
    h.x = HISPLIT(gb0.x, gb0.y); h.y = HISPLIT(gb0.z, gb0.w);
    h.z = HISPLIT(gb1.x, gb1.y); h.w = HISPLIT(gb1.z, gb1.w);
    l.x = LOSPLIT(gb0.x, gb0.y); l.y = LOSPLIT(gb0.z, gb0.w);
    l.z = LOSPLIT(gb1.x, gb1.y); l.w = LOSPLIT(gb1.z, gb1.w);
    *(uint4*)&Bh_s[swidx] = h; *(uint4*)&Bl_s[swidx] = l;
    h.x = HISPLIT(gb2.x, gb2.y); h.y = HISPLIT(gb2.z, gb2.w);
    h.z = HISPLIT(gb3.x, gb3.y); h.w = HISPLIT(gb3.z, gb3.w);
    l.x = LOSPLIT(gb2.x, gb2.y); l.y = LOSPLIT(gb2.z, gb2.w);
    l.z = LOSPLIT(gb3.x, gb3.y); l.w = LOSPLIT(gb3.z, gb3.w);
    *(uint4*)&Bh_s[swidx + 4] = h; *(uint4*)&Bl_s[swidx + 4] = l;

    __syncthreads();

    // issue NEXT tile's global loads (latency hides under MFMA below)
    if (tt + 1 < nt) LOADT((tt + 1) << 5);

    // ---- compute from LDS: pure ds_read_b128 + MFMA ----
    short8 ah[4], al[4], bh[4], bl[4];
#pragma unroll
    for (int mf = 0; mf < 4; ++mf) {
      const int idx = (wr * 64 + mf * 16 + lr) * LROW + kg * 4;
      ah[mf] = *(const short8*)&Ah_s[idx];
      al[mf] = *(const short8*)&Al_s[idx];
    }
#pragma unroll
    for (int nf = 0; nf < 4; ++nf) {
      const int idx = (wc * 64 + nf * 16 + lr) * LROW + kg * 4;
      bh[nf] = *(const short8*)&Bh_s[idx];
      bl[nf] = *(const short8*)&Bl_s[idx];
    }
#pragma unroll
    for (int nf = 0; nf < 4; ++nf)
#pragma unroll
      for (int mf = 0; mf < 4; ++mf) {
        acc[mf][nf] = __builtin_amdgcn_mfma_f32_16x16x32_bf16(
            ah[mf], bh[nf], acc[mf][nf], 0, 0, 0);
        acc[mf][nf] = __builtin_amdgcn_mfma_f32_16x16x32_bf16(
            al[mf], bh[nf], acc[mf][nf], 0, 0, 0);
        acc[mf][nf] = __builtin_amdgcn_mfma_f32_16x16x32_bf16(
            ah[mf], bl[nf], acc[mf][nf], 0, 0, 0);
      }
    __syncthreads();
  }
#undef LOADT
#undef HISPLIT
#undef LOSPLIT

  // ---- epilogue ----
  if (EPI == 2) {
    u32* Ct = (u32*)C_;
#pragma unroll
    for (int mf = 0; mf < 4; ++mf)
#pragma unroll
      for (int nf = 0; nf < 4; ++nf) {
        const int gr = m0 + wr * 64 + mf * 16 + (lane >> 4) * 4;
        const int gc = n0 + wc * 64 + nf * 16 + lr;
        const int bb = gr >> 11, ss = gr & 2047;
        uint4 o;
        o.x = packhl(acc[mf][nf][0]); o.y = packhl(acc[mf][nf][1]);
        o.z = packhl(acc[mf][nf][2]); o.w = packhl(acc[mf][nf][3]);
        *(uint4*)(Ct + (long long)bb * N * 2048 + (long long)gc * 2048 + ss) = o;
      }
  } else {
    const long long cb = (long long)b * sC;
#pragma unroll
    for (int mf = 0; mf < 4; ++mf)
#pragma unroll
      for (int nf = 0; nf < 4; ++nf) {
        const int gr0 = m0 + wr * 64 + mf * 16 + (lane >> 4) * 4;
        const int gc = n0 + wc * 64 + nf * 16 + lr;
#pragma unroll
        for (int i = 0; i < 4; ++i) {
          float v = acc[mf][nf][i] * alpha;
          if (EPI == 3) { v += bias[gc]; v = fmaxf(v, 0.f); }
          if (EPI == 0)
            *((float*)C_ + cb + (long long)(gr0 + i) * N + gc) = v;
          else
            *((u32*)C_ + cb + (long long)(gr0 + i) * N + gc) = packhl(v);
        }
      }
  }
}

// ---------------------------------------------------------------------------
// Row softmax over ncols=2048 fp32; writes PACKED u32 in place.
// ---------------------------------------------------------------------------
__global__ __launch_bounds__(256) void softmax_rows(
    float* __restrict__ S_, int ncols, int qcc, int causal, int qofs) {
  __shared__ float red[4];
  const long long r = blockIdx.x;
  const int q = qofs + (int)(r % qcc);
  float* row = S_ + r * (long long)ncols;
  const int tid = threadIdx.x;
  float v[8];
  *(float4*)&v[0] = *(const float4*)(row + tid * 8);
  *(float4*)&v[4] = *(const float4*)(row + tid * 8 + 4);
  if (causal) {
#pragma unroll
    for (int j = 0; j < 8; ++j)
      if (tid * 8 + j > q) v[j] = -INFINITY;
  }
  float m = -INFINITY;
#pragma unroll
  for (int j = 0; j < 8; ++j) m = fmaxf(m, v[j]);
  m = block_reduce_max(m, red);
  float s = 0.f;
#pragma unroll
  for (int j = 0; j < 8; ++j) {
    v[j] = __expf(v[j] - m);
    s += v[j];
  }
  s = block_reduce_sum(s, red);
  const float inv = 1.0f / s;
  u32* rowp = (u32*)row;
  uint4 o0, o1;
  o0.x = packhl(v[0] * inv); o0.y = packhl(v[1] * inv);
  o0.z = packhl(v[2] * inv); o0.w = packhl(v[3] * inv);
  o1.x = packhl(v[4] * inv); o1.y = packhl(v[5] * inv);
  o1.z = packhl(v[6] * inv); o1.w = packhl(v[7] * inv);
  *(uint4*)(rowp + tid * 8) = o0;
  *(uint4*)(rowp + tid * 8 + 4) = o1;
}

// ---------------------------------------------------------------------------
// add_ln: out[r] = (relu?) LN(X[r] + Y[r]).  Packed/fp32 in/out per flags.
// ---------------------------------------------------------------------------
template <bool XP, bool YP, bool OUTP, bool RELU>
__global__ __launch_bounds__(256) void add_ln(
    const void* __restrict__ X_, const void* __restrict__ Y_,
    const float* __restrict__ gamma, const float* __restrict__ beta,
    void* __restrict__ out_, int E) {
  __shared__ float red[4];
  const long long r = blockIdx.x;
  const int tid = threadIdx.x;
  const float invE = 1.0f / (float)E;
  float v[4];
  if (XP) {
    const uint4 a = *(const uint4*)((const u32*)X_ + r * E + tid * 4);
    v[0] = unpackhl(a.x); v[1] = unpackhl(a.y);
    v[2] = unpackhl(a.z); v[3] = unpackhl(a.w);
  } else {
    const float4 a = *(const float4*)((const float*)X_ + r * E + tid * 4);
    v[0] = a.x; v[1] = a.y; v[2] = a.z; v[3] = a.w;
  }
  if (YP) {
    const uint4 bq = *(const uint4*)((const u32*)Y_ + r * E + tid * 4);
    v[0] += unpackhl(bq.x); v[1] += unpackhl(bq.y);
    v[2] += unpackhl(bq.z); v[3] += unpackhl(bq.w);
  } else {
    const float4 bq = *(const float4*)((const float*)Y_ + r * E + tid * 4);
    v[0] += bq.x; v[1] += bq.y; v[2] += bq.z; v[3] += bq.w;
  }
  float s = v[0] + v[1] + v[2] + v[3];
  s = block_reduce_sum(s, red);
  const float mu = s * invE;
  float d[4], sq = 0.f;
#pragma unroll
  for (int j = 0; j < 4; ++j) {
    d[j] = v[j] - mu;
    sq += d[j] * d[j];
  }
  sq = block_reduce_sum(sq, red);
  const float rs = rsqrtf(sq * invE + 1e-3f);
  const float4 g = *(const float4*)(gamma + tid * 4);
  const float4 be = *(const float4*)(beta + tid * 4);
  float o[4];
  o[0] = g.x * d[0] * rs + be.x; o[1] = g.y * d[1] * rs + be.y;
  o[2] = g.z * d[2] * rs + be.z; o[3] = g.w * d[3] * rs + be.w;
  if (RELU) {
#pragma unroll
    for (int j = 0; j < 4; ++j) o[j] = fmaxf(o[j], 0.f);
  }
  if (OUTP) {
    uint4 w;
    w.x = packhl(o[0]); w.y = packhl(o[1]);
    w.z = packhl(o[2]); w.w = packhl(o[3]);
    *(uint4*)((u32*)out_ + r * E + tid * 4) = w;
  } else {
    float4 w;
    w.x = o[0]; w.y = o[1]; w.z = o[2]; w.w = o[3];
    *(float4*)((float*)out_ + r * E + tid * 4) = w;
  }
}

// ---------------------------------------------------------------------------
// Weight transpose+pack: W[1024][1024] fp32 -> out[widx][n][k] packed u32.
// ---------------------------------------------------------------------------
__global__ __launch_bounds__(256) void wpack_t(
    const float* __restrict__ W0, const float* __restrict__ W1_,
    const float* __restrict__ W2, const float* __restrict__ W3,
    const float* __restrict__ W4, const float* __restrict__ W5,
    const float* __restrict__ W6, u32* __restrict__ out) {
  __shared__ float tile[64][65];
  const int wi = blockIdx.z;
  const float* W = wi == 0 ? W0 : wi == 1 ? W1_ : wi == 2 ? W2
                 : wi == 3 ? W3 : wi == 4 ? W4 : wi == 5 ? W5 : W6;
  const int k0 = blockIdx.y * 64, n0 = blockIdx.x * 64;
  const int tr = threadIdx.x >> 4, tc4 = (threadIdx.x & 15) * 4;
#pragma unroll
  for (int i = 0; i < 4; ++i) {
    const int row = tr * 4 + i;
    const float4 v = *(const float4*)(W + (long long)(k0 + row) * 1024 + n0 + tc4);
    tile[row][tc4 + 0] = v.x; tile[row][tc4 + 1] = v.y;
    tile[row][tc4 + 2] = v.z; tile[row][tc4 + 3] = v.w;
  }
  __syncthreads();
  u32* o = out + (long long)wi * 1048576;
#pragma unroll
  for (int i = 0; i < 4; ++i) {
    const int nrow = tr * 4 + i;
    uint4 w;
    w.x = packhl(tile[tc4 + 0][nrow]);
    w.y = packhl(tile[tc4 + 1][nrow]);
    w.z = packhl(tile[tc4 + 2][nrow]);
    w.w = packhl(tile[tc4 + 3][nrow]);
    *(uint4*)(o + (long long)(n0 + nrow) * 1024 + k0 + tc4) = w;
  }
}

extern "C" void kernel_launch(void* const* d_in, const int* in_sizes, int n_in,
                              void* d_out, int out_size, void* d_ws,
                              size_t ws_size, hipStream_t stream) {
  const int B = 8, S = 2048, E = 1024;
  const int M = B * S;

  const float* inputs = (const float*)d_in[0];
  const float* context = (const float*)d_in[1];
  const float* Wq = (const float*)d_in[2];
  const float* Wk = (const float*)d_in[3];
  const float* Wv = (const float*)d_in[4];
  const float* Wcq = (const float*)d_in[5];
  const float* Wck = (const float*)d_in[6];
  const float* Wcv = (const float*)d_in[7];
  const float* gamma = (const float*)d_in[8];
  const float* beta = (const float*)d_in[9];
  const float* W1 = (const float*)d_in[10];
  const float* b1 = (const float*)d_in[11];
  float* out = (float*)d_out;

  char* wsb = (char*)d_ws;
  const size_t BUF = (size_t)M * E * 4;  // 64 MB
  u32* s1 = (u32*)wsb;
  u32* s2 = (u32*)(wsb + BUF);
  u32* s3 = (u32*)(wsb + 2 * BUF);
  u32* wt = (u32*)(wsb + 3 * BUF);
  const size_t WTB = (size_t)7 * 1024 * 1024 * 4;  // 28 MB
  float* sc = (float*)(wsb + 3 * BUF + WTB);

  int qc = 512;
  while (qc > 128 && 3 * BUF + WTB + (size_t)B * qc * S * 4 > ws_size) qc >>= 1;
  const int nchunks = S / qc;

  const long long sSE = (long long)S * E;
  const long long sCS = (long long)qc * S;
  const long long sES = (long long)E * S;
  const float sscale = 0.03125f;

  dim3 blk(256);
  dim3 gProj(8, 128, 1);
  dim3 gScore(16, qc / 128, B);
  dim3 gPV(8, qc / 128, B);
  dim3 gRowC(B * qc);
  dim3 gRow(M);

  // weights: transpose + pack
  wpack_t<<<dim3(16, 16, 7), blk, 0, stream>>>(Wq, Wk, Wv, Wcq, Wck, Wcv, W1, wt);
  const u32* WqT = wt;
  const u32* WkT = wt + 1 * 1048576;
  const u32* WvT = wt + 2 * 1048576;
  const u32* WcqT = wt + 3 * 1048576;
  const u32* WckT = wt + 4 * 1048576;
  const u32* WcvT = wt + 5 * 1048576;
  const u32* W1T = wt + 6 * 1048576;

  // --- self-attention projections (A = inputs fp32) ---
  gemm_hl<false, 1, false, false><<<gProj, blk, 0, stream>>>(
      inputs, WqT, s1, nullptr, E, E, 0, 0, 0, 1.f, 0);
  gemm_hl<false, 1, false, false><<<gProj, blk, 0, stream>>>(
      inputs, WkT, s2, nullptr, E, E, 0, 0, 0, 1.f, 0);
  gemm_hl<false, 2, false, false><<<gProj, blk, 0, stream>>>(
      inputs, WvT, s3, nullptr, E, E, 0, 0, 0, 1.f, 0);  // Vt packed

  // --- self-attention (causal), chunked; O overwrites Q chunk ---
  for (int c = 0; c < nchunks; ++c) {
    const int mofs = c * qc;
    gemm_hl<true, 0, true, false><<<gScore, blk, 0, stream>>>(
        s1 + (long long)mofs * E, s2, sc, nullptr, S, E, sSE, sSE, sCS,
        sscale, mofs);
    softmax_rows<<<gRowC, blk, 0, stream>>>(sc, S, qc, 1, mofs);
    gemm_hl<true, 1, false, true><<<gPV, blk, 0, stream>>>(
        sc, s3, s1 + (long long)mofs * E, nullptr, E, S, sCS, sES, sSE,
        1.f, mofs);
  }
  // h = LN(O + inputs) -> s1 packed (in place)
  add_ln<true, false, true, false><<<gRow, blk, 0, stream>>>(
      s1, inputs, gamma, beta, s1, E);

  // --- cross projections ---
  gemm_hl<true, 1, false, false><<<gProj, blk, 0, stream>>>(
      s1, WcqT, s2, nullptr, E, E, 0, 0, 0, 1.f, 0);  // Q2
  gemm_hl<false, 1, false, false><<<gProj, blk, 0, stream>>>(
      context, WckT, s3, nullptr, E, E, 0, 0, 0, 1.f, 0);  // K2
  gemm_hl<false, 2, false, false><<<gProj, blk, 0, stream>>>(
      context, WcvT, d_out, nullptr, E, E, 0, 0, 0, 1.f, 0);  // V2t in d_out

  // --- cross-attention, chunked; O2 overwrites Q2 chunk ---
  for (int c = 0; c < nchunks; ++c) {
    const int mofs = c * qc;
    gemm_hl<true, 0, false, false><<<gScore, blk, 0, stream>>>(
        s2 + (long long)mofs * E, s3, sc, nullptr, S, E, sSE, sSE, sCS,
        sscale, 0);
    softmax_rows<<<gRowC, blk, 0, stream>>>(sc, S, qc, 0, mofs);
    gemm_hl<true, 1, false, false><<<gPV, blk, 0, stream>>>(
        sc, (const u32*)d_out, s2 + (long long)mofs * E, nullptr, E, S, sCS,
        sES, sSE, 1.f, 0);
  }
  // h2 = LN(O2 + h) -> s1 packed (in place over h)
  add_ln<true, true, true, false><<<gRow, blk, 0, stream>>>(
      s2, s1, gamma, beta, s1, E);

  // --- FFN: f = relu(h2 @ W1 + b1) -> s2 packed ---
  gemm_hl<true, 3, false, false><<<gProj, blk, 0, stream>>>(
      s1, W1T, s2, b1, E, E, 0, 0, 0, 1.f, 0);

  // out = relu(LN(f + h2)) -> d_out fp32
  add_ln<true, true, false, true><<<gRow, blk, 0, stream>>>(
      s2, s1, gamma, beta, out, E);
}

// Round 11
// 2078.136 us; speedup vs baseline: 3.6287x; 1.1690x over previous
//
#include <hip/hip_runtime.h>
#include <math.h>

// ---------------------------------------------------------------------------
// Transformer block (B=8, S=2048, E=1024) — split-bf16 MFMA, producer-split
// plane format.  Every tensor value -> bf16 hi + bf16 lo (residual).
// GLOBAL layout per row, per 32-elem K-tile: [16 u32 hi-pair words | 16 u32
// lo-pair words]  (32 words / 32 elems = 4B/elem, same sizes as before).
// GEMM staging = pure load+ds_write (no VALU); split paid once in producers.
// GEMM: C ~= Ah*Bh + Al*Bh + Ah*Bl (3 MFMA passes, bit-identical to r10).
// ---------------------------------------------------------------------------

typedef unsigned int u32;
typedef __attribute__((ext_vector_type(8))) short short8;
typedef __attribute__((ext_vector_type(4))) float f32x4;

#define HISPLIT(p0, p1) (((p0) & 0xFFFFu) | ((p1) << 16))
#define LOSPLIT(p0, p1) (((p0) >> 16) | ((p1) & 0xFFFF0000u))

__device__ __forceinline__ u32 packhl(float x) {
  u32 u = __float_as_uint(x);
  float hf = __uint_as_float(u & 0xFFFF0000u);   // truncated-bf16 hi
  u32 lu = __float_as_uint(x - hf);              // exact residual
  return (u >> 16) | (lu & 0xFFFF0000u);         // low16 = hi, high16 = lo
}
__device__ __forceinline__ float af(u32 u) { return __uint_as_float(u); }

__device__ __forceinline__ float wave_reduce_sum(float v) {
#pragma unroll
  for (int m = 32; m >= 1; m >>= 1) v += __shfl_xor(v, m, 64);
  return v;
}
__device__ __forceinline__ float wave_reduce_max(float v) {
#pragma unroll
  for (int m = 32; m >= 1; m >>= 1) v = fmaxf(v, __shfl_xor(v, m, 64));
  return v;
}
__device__ __forceinline__ float block_reduce_sum(float v, float* red) {
  v = wave_reduce_sum(v);
  if ((threadIdx.x & 63) == 0) red[threadIdx.x >> 6] = v;
  __syncthreads();
  const float r = red[0] + red[1] + red[2] + red[3];
  __syncthreads();
  return r;
}
__device__ __forceinline__ float block_reduce_max(float v, float* red) {
  v = wave_reduce_max(v);
  if ((threadIdx.x & 63) == 0) red[threadIdx.x >> 6] = v;
  __syncthreads();
  const float r = fmaxf(fmaxf(red[0], red[1]), fmaxf(red[2], red[3]));
  __syncthreads();
  return r;
}

#define LROW 20  // u32 words per LDS plane row (32 used + pad)

// ---------------------------------------------------------------------------
// gemm_hl: C[b] = alpha * A[b](MxK) * Bt[b](NxK)^T, K-contiguous operands.
// A plane-format u32 if APACK else fp32 (split during staging). Bt plane u32.
// EPI: 0 fp32*alpha out; 1 plane out; 2 plane TRANSPOSED out; 3 bias+relu.
// ---------------------------------------------------------------------------
template <bool APACK, int EPI, bool CAUSAL, bool KCAP>
__global__ __launch_bounds__(256) void gemm_hl(
    const void* __restrict__ A_, const u32* __restrict__ Bt,
    void* __restrict__ C_, const float* __restrict__ bias,
    int N, int K, long long sA, long long sB, long long sC,
    float alpha, int mofs) {
  const int b = blockIdx.z;
  const int m0 = blockIdx.y * 128;
  const int n0 = blockIdx.x * 128;
  if (CAUSAL && n0 >= mofs + m0 + 128) return;
  const u32* Ap = (const u32*)A_ + (long long)b * sA;
  const float* Af = (const float*)A_ + (long long)b * sA;
  const u32* Bp = Bt + (long long)b * sB;
  int Keff = K;
  if (KCAP) {
    int ke = mofs + m0 + 128;
    Keff = ke < K ? ke : K;
  }
  const int nt = Keff >> 5;  // K-steps of 32

  __shared__ u32 Ah_s[128 * LROW];
  __shared__ u32 Al_s[128 * LROW];
  __shared__ u32 Bh_s[128 * LROW];
  __shared__ u32 Bl_s[128 * LROW];

  const int t = threadIdx.x;
  const int lane = t & 63, wv = t >> 6;
  const int wr = wv >> 1, wc = wv & 1;
  const int lr = lane & 15, kg = lane >> 4;
  const int srow = t >> 1;       // staging row 0..127
  const int half = t & 1;        // 0 = hi plane, 1 = lo plane

  f32x4 acc[4][4];
#pragma unroll
  for (int i = 0; i < 4; ++i)
#pragma unroll
    for (int j = 0; j < 4; ++j) {
      acc[i][j][0] = 0.f; acc[i][j][1] = 0.f;
      acc[i][j][2] = 0.f; acc[i][j][3] = 0.f;
    }

  // in-flight tile registers
  uint4 ga0, ga1, ga2, ga3, gb0, gb1, gb2, gb3;
  float4 fa0, fa1, fa2, fa3;

  // plane format: tile t of row r starts at word r*K + t*32; hi at +0, lo +16
  const long long arow = (long long)(m0 + srow) * K + half * 16;
  const long long brow = (long long)(n0 + srow) * K + half * 16;

#define LOADT(k0)                                                   \
  do {                                                              \
    if (APACK) {                                                    \
      ga0 = *(const uint4*)(Ap + arow + (k0));                      \
      ga1 = *(const uint4*)(Ap + arow + (k0) + 4);                  \
      ga2 = *(const uint4*)(Ap + arow + (k0) + 8);                  \
      ga3 = *(const uint4*)(Ap + arow + (k0) + 12);                 \
    } else {                                                        \
      fa0 = *(const float4*)(Af + arow + (k0));                     \
      fa1 = *(const float4*)(Af + arow + (k0) + 4);                 \
      fa2 = *(const float4*)(Af + arow + (k0) + 8);                 \
      fa3 = *(const float4*)(Af + arow + (k0) + 12);                \
    }                                                               \
    gb0 = *(const uint4*)(Bp + brow + (k0));                        \
    gb1 = *(const uint4*)(Bp + brow + (k0) + 4);                    \
    gb2 = *(const uint4*)(Bp + brow + (k0) + 8);                    \
    gb3 = *(const uint4*)(Bp + brow + (k0) + 12);                   \
  } while (0)

  LOADT(0);

  u32* dA = half ? Al_s : Ah_s;
  u32* dB = half ? Bl_s : Bh_s;
  const int wbase = srow * LROW;

  for (int tt = 0; tt < nt; ++tt) {
    if (APACK) {
      // pure ds_write: this thread owns the full (hi or lo) half-row
      *(uint4*)&dA[wbase + 0] = ga0;
      *(uint4*)&dA[wbase + 4] = ga1;
      *(uint4*)&dA[wbase + 8] = ga2;
      *(uint4*)&dA[wbase + 12] = ga3;
    } else {
      // fp32 A: split 16 elems (K-half selected by `half`) into planes
      u32 pk[16];
      pk[0] = packhl(fa0.x); pk[1] = packhl(fa0.y);
      pk[2] = packhl(fa0.z); pk[3] = packhl(fa0.w);
      pk[4] = packhl(fa1.x); pk[5] = packhl(fa1.y);
      pk[6] = packhl(fa1.z); pk[7] = packhl(fa1.w);
      pk[8] = packhl(fa2.x); pk[9] = packhl(fa2.y);
      pk[10] = packhl(fa2.z); pk[11] = packhl(fa2.w);
      pk[12] = packhl(fa3.x); pk[13] = packhl(fa3.y);
      pk[14] = packhl(fa3.z); pk[15] = packhl(fa3.w);
      uint4 h, l;
      h.x = HISPLIT(pk[0], pk[1]); h.y = HISPLIT(pk[2], pk[3]);
      h.z = HISPLIT(pk[4], pk[5]); h.w = HISPLIT(pk[6], pk[7]);
      l.x = LOSPLIT(pk[0], pk[1]); l.y = LOSPLIT(pk[2], pk[3]);
      l.z = LOSPLIT(pk[4], pk[5]); l.w = LOSPLIT(pk[6], pk[7]);
      *(uint4*)&Ah_s[wbase + half * 8] = h;
      *(uint4*)&Al_s[wbase + half * 8] = l;
      h.x = HISPLIT(pk[8], pk[9]); h.y = HISPLIT(pk[10], pk[11]);
      h.z = HISPLIT(pk[12], pk[13]); h.w = HISPLIT(pk[14], pk[15]);
      l.x = LOSPLIT(pk[8], pk[9]); l.y = LOSPLIT(pk[10], pk[11]);
      l.z = LOSPLIT(pk[12], pk[13]); l.w = LOSPLIT(pk[14], pk[15]);
      *(uint4*)&Ah_s[wbase + half * 8 + 4] = h;
      *(uint4*)&Al_s[wbase + half * 8 + 4] = l;
    }
    // B is always plane format: pure ds_write
    *(uint4*)&dB[wbase + 0] = gb0;
    *(uint4*)&dB[wbase + 4] = gb1;
    *(uint4*)&dB[wbase + 8] = gb2;
    *(uint4*)&dB[wbase + 12] = gb3;

    __syncthreads();

    // issue NEXT tile's global loads (latency hides under MFMA below)
    if (tt + 1 < nt) LOADT((tt + 1) << 5);

    // ---- compute from LDS: pure ds_read_b128 + MFMA ----
    short8 ah[4], al[4], bh[4], bl[4];
#pragma unroll
    for (int mf = 0; mf < 4; ++mf) {
      const int idx = (wr * 64 + mf * 16 + lr) * LROW + kg * 4;
      ah[mf] = *(const short8*)&Ah_s[idx];
      al[mf] = *(const short8*)&Al_s[idx];
    }
#pragma unroll
    for (int nf = 0; nf < 4; ++nf) {
      const int idx = (wc * 64 + nf * 16 + lr) * LROW + kg * 4;
      bh[nf] = *(const short8*)&Bh_s[idx];
      bl[nf] = *(const short8*)&Bl_s[idx];
    }
#pragma unroll
    for (int nf = 0; nf < 4; ++nf)
#pragma unroll
      for (int mf = 0; mf < 4; ++mf) {
        acc[mf][nf] = __builtin_amdgcn_mfma_f32_16x16x32_bf16(
            ah[mf], bh[nf], acc[mf][nf], 0, 0, 0);
        acc[mf][nf] = __builtin_amdgcn_mfma_f32_16x16x32_bf16(
            al[mf], bh[nf], acc[mf][nf], 0, 0, 0);
        acc[mf][nf] = __builtin_amdgcn_mfma_f32_16x16x32_bf16(
            ah[mf], bl[nf], acc[mf][nf], 0, 0, 0);
      }
    __syncthreads();
  }
#undef LOADT

  // ---- epilogue ----
  if (EPI == 2) {
    // transposed plane out: consumer-row = gc (pitch 2048 elems = S), k = ss
    u32* Ct = (u32*)C_;
#pragma unroll
    for (int mf = 0; mf < 4; ++mf)
#pragma unroll
      for (int nf = 0; nf < 4; ++nf) {
        const int gr = m0 + wr * 64 + mf * 16 + (lane >> 4) * 4;
        const int gc = n0 + wc * 64 + nf * 16 + lr;
        const int bb = gr >> 11, ss = gr & 2047;
        u32 p0 = packhl(acc[mf][nf][0]);
        u32 p1 = packhl(acc[mf][nf][1]);
        u32 p2 = packhl(acc[mf][nf][2]);
        u32 p3 = packhl(acc[mf][nf][3]);
        const long long w = (long long)bb * N * 2048 + (long long)gc * 2048 +
                            ((ss >> 5) * 32 + ((ss & 31) >> 1));
        uint2 hi, lo;
        hi.x = HISPLIT(p0, p1); hi.y = HISPLIT(p2, p3);
        lo.x = LOSPLIT(p0, p1); lo.y = LOSPLIT(p2, p3);
        *(uint2*)(Ct + w) = hi;
        *(uint2*)(Ct + w + 16) = lo;
      }
  } else if (EPI == 0) {
    float* Cf = (float*)C_ + (long long)b * sC;
#pragma unroll
    for (int mf = 0; mf < 4; ++mf)
#pragma unroll
      for (int nf = 0; nf < 4; ++nf) {
        const int gr0 = m0 + wr * 64 + mf * 16 + (lane >> 4) * 4;
        const int gc = n0 + wc * 64 + nf * 16 + lr;
#pragma unroll
        for (int i = 0; i < 4; ++i)
          Cf[(long long)(gr0 + i) * N + gc] = acc[mf][nf][i] * alpha;
      }
  } else {
    // EPI 1/3: plane-format out via ushort stores
    unsigned short* Cs = (unsigned short*)C_;
    const long long cb2 = (long long)b * sC * 2;  // ushort units
#pragma unroll
    for (int mf = 0; mf < 4; ++mf)
#pragma unroll
      for (int nf = 0; nf < 4; ++nf) {
        const int gr0 = m0 + wr * 64 + mf * 16 + (lane >> 4) * 4;
        const int gc = n0 + wc * 64 + nf * 16 + lr;
        const long long cofs = (gc >> 5) * 64 + (gc & 31);
#pragma unroll
        for (int i = 0; i < 4; ++i) {
          float v = acc[mf][nf][i] * alpha;
          if (EPI == 3) { v += bias[gc]; v = fmaxf(v, 0.f); }
          const u32 pk = packhl(v);
          const long long idx = cb2 + (long long)(gr0 + i) * (2 * N) + cofs;
          Cs[idx] = (unsigned short)pk;          // hi plane
          Cs[idx + 32] = (unsigned short)(pk >> 16);  // lo plane
        }
      }
  }
}

// ---------------------------------------------------------------------------
// Row softmax over ncols=2048 fp32; writes PLANE-format u32 in place.
// ---------------------------------------------------------------------------
__global__ __launch_bounds__(256) void softmax_rows(
    float* __restrict__ S_, int ncols, int qcc, int causal, int qofs) {
  __shared__ float red[4];
  const long long r = blockIdx.x;
  const int q = qofs + (int)(r % qcc);
  float* row = S_ + r * (long long)ncols;
  const int tid = threadIdx.x;
  float v[8];
  *(float4*)&v[0] = *(const float4*)(row + tid * 8);
  *(float4*)&v[4] = *(const float4*)(row + tid * 8 + 4);
  if (causal) {
#pragma unroll
    for (int j = 0; j < 8; ++j)
      if (tid * 8 + j > q) v[j] = -INFINITY;
  }
  float m = -INFINITY;
#pragma unroll
  for (int j = 0; j < 8; ++j) m = fmaxf(m, v[j]);
  m = block_reduce_max(m, red);
  float s = 0.f;
#pragma unroll
  for (int j = 0; j < 8; ++j) {
    v[j] = __expf(v[j] - m);
    s += v[j];
  }
  s = block_reduce_sum(s, red);  // barrier inside: all reads done before writes
  const float inv = 1.0f / s;
  u32 pk[8];
#pragma unroll
  for (int j = 0; j < 8; ++j) pk[j] = packhl(v[j] * inv);
  u32* rw = (u32*)row;
  const int wofs = (tid >> 2) * 32 + (tid & 3) * 4;
  uint4 hi, lo;
  hi.x = HISPLIT(pk[0], pk[1]); hi.y = HISPLIT(pk[2], pk[3]);
  hi.z = HISPLIT(pk[4], pk[5]); hi.w = HISPLIT(pk[6], pk[7]);
  lo.x = LOSPLIT(pk[0], pk[1]); lo.y = LOSPLIT(pk[2], pk[3]);
  lo.z = LOSPLIT(pk[4], pk[5]); lo.w = LOSPLIT(pk[6], pk[7]);
  *(uint4*)(rw + wofs) = hi;
  *(uint4*)(rw + wofs + 16) = lo;
}

// ---------------------------------------------------------------------------
// add_ln: out[r] = (relu?) LN(X[r] + Y[r]).  Plane/fp32 in/out per flags.
// Thread handles elems e = (tid>>3)*32 + (tid&7)*4 + {0..3} (plane path) which
// equals tid*4 + ... consistent with fp32 path's tid*4 ordering per row.
// ---------------------------------------------------------------------------
template <bool XP, bool YP, bool OUTP, bool RELU>
__global__ __launch_bounds__(256) void add_ln(
    const void* __restrict__ X_, const void* __restrict__ Y_,
    const float* __restrict__ gamma, const float* __restrict__ beta,
    void* __restrict__ out_, int E) {
  __shared__ float red[4];
  const long long r = blockIdx.x;
  const int tid = threadIdx.x;
  const float invE = 1.0f / (float)E;
  const int e0 = (tid >> 3) * 32 + (tid & 7) * 4;  // first elem (plane path)
  const int wofs = (tid >> 3) * 32 + (tid & 7) * 2;
  float v[4];
  if (XP) {
    const uint2 hi = *(const uint2*)((const u32*)X_ + r * E + wofs);
    const uint2 lo = *(const uint2*)((const u32*)X_ + r * E + wofs + 16);
    v[0] = af(hi.x << 16) + af(lo.x << 16);
    v[1] = af(hi.x & 0xFFFF0000u) + af(lo.x & 0xFFFF0000u);
    v[2] = af(hi.y << 16) + af(lo.y << 16);
    v[3] = af(hi.y & 0xFFFF0000u) + af(lo.y & 0xFFFF0000u);
  } else {
    const float4 a = *(const float4*)((const float*)X_ + r * E + e0);
    v[0] = a.x; v[1] = a.y; v[2] = a.z; v[3] = a.w;
  }
  if (YP) {
    const uint2 hi = *(const uint2*)((const u32*)Y_ + r * E + wofs);
    const uint2 lo = *(const uint2*)((const u32*)Y_ + r * E + wofs + 16);
    v[0] += af(hi.x << 16) + af(lo.x << 16);
    v[1] += af(hi.x & 0xFFFF0000u) + af(lo.x & 0xFFFF0000u);
    v[2] += af(hi.y << 16) + af(lo.y << 16);
    v[3] += af(hi.y & 0xFFFF0000u) + af(lo.y & 0xFFFF0000u);
  } else {
    const float4 bq = *(const float4*)((const float*)Y_ + r * E + e0);
    v[0] += bq.x; v[1] += bq.y; v[2] += bq.z; v[3] += bq.w;
  }
  float s = v[0] + v[1] + v[2] + v[3];
  s = block_reduce_sum(s, red);
  const float mu = s * invE;
  float d[4], sq = 0.f;
#pragma unroll
  for (int j = 0; j < 4; ++j) {
    d[j] = v[j] - mu;
    sq += d[j] * d[j];
  }
  sq = block_reduce_sum(sq, red);
  const float rs = rsqrtf(sq * invE + 1e-3f);
  const float4 g = *(const float4*)(gamma + e0);
  const float4 be = *(const float4*)(beta + e0);
  float o[4];
  o[0] = g.x * d[0] * rs + be.x; o[1] = g.y * d[1] * rs + be.y;
  o[2] = g.z * d[2] * rs + be.z; o[3] = g.w * d[3] * rs + be.w;
  if (RELU) {
#pragma unroll
    for (int j = 0; j < 4; ++j) o[j] = fmaxf(o[j], 0.f);
  }
  if (OUTP) {
    u32 p0 = packhl(o[0]), p1 = packhl(o[1]);
    u32 p2 = packhl(o[2]), p3 = packhl(o[3]);
    uint2 hi, lo;
    hi.x = HISPLIT(p0, p1); hi.y = HISPLIT(p2, p3);
    lo.x = LOSPLIT(p0, p1); lo.y = LOSPLIT(p2, p3);
    *(uint2*)((u32*)out_ + r * E + wofs) = hi;
    *(uint2*)((u32*)out_ + r * E + wofs + 16) = lo;
  } else {
    float4 w;
    w.x = o[0]; w.y = o[1]; w.z = o[2]; w.w = o[3];
    *(float4*)((float*)out_ + r * E + e0) = w;
  }
}

// ---------------------------------------------------------------------------
// pack_planes: fp32 [rows][E] -> plane-format u32 [rows][E words].
// ---------------------------------------------------------------------------
__global__ __launch_bounds__(256) void pack_planes(
    const float* __restrict__ X, u32* __restrict__ O, int E) {
  const long long r = blockIdx.x;
  const int tid = threadIdx.x;
  const int e0 = (tid >> 3) * 32 + (tid & 7) * 4;
  const float4 f = *(const float4*)(X + r * E + e0);
  u32 p0 = packhl(f.x), p1 = packhl(f.y), p2 = packhl(f.z), p3 = packhl(f.w);
  uint2 hi, lo;
  hi.x = HISPLIT(p0, p1); hi.y = HISPLIT(p2, p3);
  lo.x = LOSPLIT(p0, p1); lo.y = LOSPLIT(p2, p3);
  const int wofs = (tid >> 3) * 32 + (tid & 7) * 2;
  *(uint2*)(O + r * E + wofs) = hi;
  *(uint2*)(O + r * E + wofs + 16) = lo;
}

// ---------------------------------------------------------------------------
// Weight transpose+pack: W[1024][1024] fp32 -> plane-format [n][k] per widx.
// ---------------------------------------------------------------------------
__global__ __launch_bounds__(256) void wpack_t(
    const float* __restrict__ W0, const float* __restrict__ W1_,
    const float* __restrict__ W2, const float* __restrict__ W3,
    const float* __restrict__ W4, const float* __restrict__ W5,
    const float* __restrict__ W6, u32* __restrict__ out) {
  __shared__ float tile[64][65];
  const int wi = blockIdx.z;
  const float* W = wi == 0 ? W0 : wi == 1 ? W1_ : wi == 2 ? W2
                 : wi == 3 ? W3 : wi == 4 ? W4 : wi == 5 ? W5 : W6;
  const int k0 = blockIdx.y * 64, n0 = blockIdx.x * 64;
  const int tr = threadIdx.x >> 4, tc4 = (threadIdx.x & 15) * 4;
#pragma unroll
  for (int i = 0; i < 4; ++i) {
    const int row = tr * 4 + i;
    const float4 v = *(const float4*)(W + (long long)(k0 + row) * 1024 + n0 + tc4);
    tile[row][tc4 + 0] = v.x; tile[row][tc4 + 1] = v.y;
    tile[row][tc4 + 2] = v.z; tile[row][tc4 + 3] = v.w;
  }
  __syncthreads();
  u32* o = out + (long long)wi * 1048576;
  const int kk = k0 + tc4;
  const int kw = (kk >> 5) * 32 + ((kk & 31) >> 1);
#pragma unroll
  for (int i = 0; i < 4; ++i) {
    const int nrow = tr * 4 + i;
    u32 p0 = packhl(tile[tc4 + 0][nrow]);
    u32 p1 = packhl(tile[tc4 + 1][nrow]);
    u32 p2 = packhl(tile[tc4 + 2][nrow]);
    u32 p3 = packhl(tile[tc4 + 3][nrow]);
    uint2 hi, lo;
    hi.x = HISPLIT(p0, p1); hi.y = HISPLIT(p2, p3);
    lo.x = LOSPLIT(p0, p1); lo.y = LOSPLIT(p2, p3);
    const long long w = (long long)(n0 + nrow) * 1024 + kw;
    *(uint2*)(o + w) = hi;
    *(uint2*)(o + w + 16) = lo;
  }
}

extern "C" void kernel_launch(void* const* d_in, const int* in_sizes, int n_in,
                              void* d_out, int out_size, void* d_ws,
                              size_t ws_size, hipStream_t stream) {
  const int B = 8, S = 2048, E = 1024;
  const int M = B * S;

  const float* inputs = (const float*)d_in[0];
  const float* context = (const float*)d_in[1];
  const float* Wq = (const float*)d_in[2];
  const float* Wk = (const float*)d_in[3];
  const float* Wv = (const float*)d_in[4];
  const float* Wcq = (const float*)d_in[5];
  const float* Wck = (const float*)d_in[6];
  const float* Wcv = (const float*)d_in[7];
  const float* gamma = (const float*)d_in[8];
  const float* beta = (const float*)d_in[9];
  const float* W1 = (const float*)d_in[10];
  const float* b1 = (const float*)d_in[11];
  float* out = (float*)d_out;

  char* wsb = (char*)d_ws;
  const size_t BUF = (size_t)M * E * 4;  // 64 MB
  u32* s1 = (u32*)wsb;
  u32* s2 = (u32*)(wsb + BUF);
  u32* s3 = (u32*)(wsb + 2 * BUF);
  u32* wt = (u32*)(wsb + 3 * BUF);
  const size_t WTB = (size_t)7 * 1024 * 1024 * 4;  // 28 MB
  float* sc = (float*)(wsb + 3 * BUF + WTB);

  int qc = 512;
  while (qc > 128 && 3 * BUF + WTB + (size_t)B * qc * S * 4 > ws_size) qc >>= 1;
  const int nchunks = S / qc;

  const long long sSE = (long long)S * E;
  const long long sCS = (long long)qc * S;
  const long long sES = (long long)E * S;
  const float sscale = 0.03125f;

  dim3 blk(256);
  dim3 gProj(8, 128, 1);
  dim3 gScore(16, qc / 128, B);
  dim3 gPV(8, qc / 128, B);
  dim3 gRowC(B * qc);
  dim3 gRow(M);

  // inputs -> plane format, parked in d_out (dead until V2t)
  pack_planes<<<gRow, blk, 0, stream>>>(inputs, (u32*)d_out, E);
  // weights: transpose + plane-pack
  wpack_t<<<dim3(16, 16, 7), blk, 0, stream>>>(Wq, Wk, Wv, Wcq, Wck, Wcv, W1, wt);
  const u32* WqT = wt;
  const u32* WkT = wt + 1 * 1048576;
  const u32* WvT = wt + 2 * 1048576;
  const u32* WcqT = wt + 3 * 1048576;
  const u32* WckT = wt + 4 * 1048576;
  const u32* WcvT = wt + 5 * 1048576;
  const u32* W1T = wt + 6 * 1048576;

  // --- self-attention projections (A = input planes in d_out) ---
  gemm_hl<true, 1, false, false><<<gProj, blk, 0, stream>>>(
      d_out, WqT, s1, nullptr, E, E, 0, 0, 0, 1.f, 0);
  gemm_hl<true, 1, false, false><<<gProj, blk, 0, stream>>>(
      d_out, WkT, s2, nullptr, E, E, 0, 0, 0, 1.f, 0);
  gemm_hl<true, 2, false, false><<<gProj, blk, 0, stream>>>(
      d_out, WvT, s3, nullptr, E, E, 0, 0, 0, 1.f, 0);  // Vt planes

  // --- self-attention (causal), chunked; O overwrites Q chunk ---
  for (int c = 0; c < nchunks; ++c) {
    const int mofs = c * qc;
    gemm_hl<true, 0, true, false><<<gScore, blk, 0, stream>>>(
        s1 + (long long)mofs * E, s2, sc, nullptr, S, E, sSE, sSE, sCS,
        sscale, mofs);
    softmax_rows<<<gRowC, blk, 0, stream>>>(sc, S, qc, 1, mofs);
    gemm_hl<true, 1, false, true><<<gPV, blk, 0, stream>>>(
        sc, s3, s1 + (long long)mofs * E, nullptr, E, S, sCS, sES, sSE,
        1.f, mofs);
  }
  // h = LN(O + inputs) -> s1 planes (in place)
  add_ln<true, false, true, false><<<gRow, blk, 0, stream>>>(
      s1, inputs, gamma, beta, s1, E);

  // --- cross projections ---
  gemm_hl<true, 1, false, false><<<gProj, blk, 0, stream>>>(
      s1, WcqT, s2, nullptr, E, E, 0, 0, 0, 1.f, 0);  // Q2
  gemm_hl<false, 1, false, false><<<gProj, blk, 0, stream>>>(
      context, WckT, s3, nullptr, E, E, 0, 0, 0, 1.f, 0);  // K2 (fp32 A)
  gemm_hl<false, 2, false, false><<<gProj, blk, 0, stream>>>(
      context, WcvT, d_out, nullptr, E, E, 0, 0, 0, 1.f, 0);  // V2t -> d_out

  // --- cross-attention, chunked; O2 overwrites Q2 chunk ---
  for (int c = 0; c < nchunks; ++c) {
    const int mofs = c * qc;
    gemm_hl<true, 0, false, false><<<gScore, blk, 0, stream>>>(
        s2 + (long long)mofs * E, s3, sc, nullptr, S, E, sSE, sSE, sCS,
        sscale, 0);
    softmax_rows<<<gRowC, blk, 0, stream>>>(sc, S, qc, 0, mofs);
    gemm_hl<true, 1, false, false><<<gPV, blk, 0, stream>>>(
        sc, (const u32*)d_out, s2 + (long long)mofs * E, nullptr, E, S, sCS,
        sES, sSE, 1.f, 0);
  }
  // h2 = LN(O2 + h) -> s1 planes (in place over h)
  add_ln<true, true, true, false><<<gRow, blk, 0, stream>>>(
      s2, s1, gamma, beta, s1, E);

  // --- FFN: f = relu(h2 @ W1 + b1) -> s2 planes ---
  gemm_hl<true, 3, false, false><<<gProj, blk, 0, stream>>>(
      s1, W1T, s2, b1, E, E, 0, 0, 0, 1.f, 0);

  // out = relu(LN(f + h2)) -> d_out fp32 (V2 planes dead by now)
  add_ln<true, true, false, true><<<gRow, blk, 0, stream>>>(
      s2, s1, gamma, beta, out, E);
}